// Round 7
// baseline (415.698 us; speedup 1.0000x reference)
//
#include <hip/hip_runtime.h>

typedef unsigned short u16;
typedef __bf16 bf16x8 __attribute__((ext_vector_type(8)));
typedef float f32x4 __attribute__((ext_vector_type(4)));

#define T_TOK 2048
#define HID   1024
#define NEXP  32
#define IM    512
#define SI    2048
#define TOPK  6
#define PLAN_MAX 160
#define CVT_BLOCKS 19456   // 9,961,472 float4 / 512 per block

// exact RNE float->bf16
__device__ __forceinline__ u16 f2bf(float f){
  unsigned u = __float_as_uint(f);
  u += 0x7FFFu + ((u >> 16) & 1u);
  return (u16)(u >> 16);
}

// async global->LDS, 16B per lane. LDS dest must be wave-uniform base + lane*16.
__device__ __forceinline__ void gll16(const void* g, void* l){
  __builtin_amdgcn_global_load_lds((const __attribute__((address_space(1))) void*)g,
                                   (__attribute__((address_space(3))) void*)l, 16, 0, 0);
}

__device__ __forceinline__ ushort4 cvt4(float4 v){
  ushort4 o; o.x = f2bf(v.x); o.y = f2bf(v.y); o.z = f2bf(v.z); o.w = f2bf(v.w);
  return o;
}

// phase1: blocks [0,CVT_BLOCKS) convert fp32->bf16 (512 float4/block, 2/thread);
// blocks [CVT_BLOCKS, +512) run the router (4 tokens/block, 1 wave/token).
__global__ __launch_bounds__(256) void phase1_kernel(const float4* __restrict__ s0, // x      524288 f4
                                                     const float4* __restrict__ s1, // upw   4194304
                                                     const float4* __restrict__ s2, // dnw   4194304
                                                     const float4* __restrict__ s3, // supw   524288
                                                     const float4* __restrict__ s4, // sdnw   524288
                                                     ushort4* __restrict__ d0,
                                                     ushort4* __restrict__ d1,
                                                     ushort4* __restrict__ d2,
                                                     ushort4* __restrict__ d3,
                                                     ushort4* __restrict__ d4,
                                                     const float* __restrict__ gate,
                                                     const float* __restrict__ ebias,
                                                     int* __restrict__ ce,
                                                     float* __restrict__ cw){
  int tid = threadIdx.x;
  if (blockIdx.x < CVT_BLOCKS){
    long i = (long)blockIdx.x * 512 + tid;       // block span (512 f4) stays in one region
    const float4* s; ushort4* d;
    if      (i <  524288L) { s = s0;            d = d0;            }
    else if (i < 4718592L) { s = s1 - 524288L;  d = d1 - 524288L;  }
    else if (i < 8912896L) { s = s2 - 4718592L; d = d2 - 4718592L; }
    else if (i < 9437184L) { s = s3 - 8912896L; d = d3 - 8912896L; }
    else                   { s = s4 - 9437184L; d = d4 - 9437184L; }
    float4 v0 = s[i];
    float4 v1 = s[i + 256];
    d[i]       = cvt4(v0);
    d[i + 256] = cvt4(v1);
    return;
  }
  // ---- router role ----
  const float* x = (const float*)s0;
  int wave = tid >> 6;
  int lane = tid & 63;
  int t = (blockIdx.x - CVT_BLOCKS) * 4 + wave;
  int e = lane & 31, half = lane >> 5;
  const float4* xv = (const float4*)(x + (size_t)t * HID);
  const float4* gv = (const float4*)(gate + (size_t)e * HID);
  double p0 = 0, p1 = 0, p2 = 0, p3 = 0;
  for (int i = half * 128; i < half * 128 + 128; i++){
    float4 a = xv[i], b = gv[i];
    p0 += (double)a.x * b.x; p1 += (double)a.y * b.y;
    p2 += (double)a.z * b.z; p3 += (double)a.w * b.w;
  }
  double acc = (p0 + p1) + (p2 + p3);
  acc += __shfl_xor(acc, 32);
  double score = 1.0 / (1.0 + exp(-acc));
  double sc = score + (double)ebias[e];
  double o1  = __shfl_xor(sc, 1);
  double hi  = fmax(sc, o1), lo = fmin(sc, o1);
  double ohi = __shfl_xor(hi, 2), olo = __shfl_xor(lo, 2);
  double gs  = (hi >= ohi) ? hi + fmax(lo, ohi) : ohi + fmax(olo, hi);
  int g = e >> 2;
  int rank = 0;
#pragma unroll
  for (int j = 0; j < 8; j++){
    double gj = __shfl(gs, j * 4);
    if (gj > gs || (gj == gs && j < g)) rank++;
  }
  double cur = (rank < 4) ? sc : 0.0;
  int sel_e[TOPK]; double sel_w[TOPK]; double wsum = 0.0;
#pragma unroll
  for (int k = 0; k < TOPK; k++){
    double bv = cur; int bi = lane;
#pragma unroll
    for (int m = 32; m >= 1; m >>= 1){
      double ov = __shfl_xor(bv, m); int oi = __shfl_xor(bi, m);
      if (ov > bv || (ov == bv && oi < bi)) { bv = ov; bi = oi; }
    }
    if ((bi & 31) == e) cur = -1e300;
    double ws = __shfl(score, bi);
    sel_e[k] = bi; sel_w[k] = ws; wsum += ws;
  }
  double scale = 2.5 / (wsum + 1e-20);
#pragma unroll
  for (int k = 0; k < TOPK; k++){
    if (lane == k){
      ce[t * TOPK + k] = sel_e[k] & 31;
      cw[t * TOPK + k] = (float)(sel_w[k] * scale);
    }
  }
}

// 32 blocks (one per expert): ordered compaction via ballot prefix scan.
__global__ __launch_bounds__(256) void build_kernel(const int* __restrict__ ce,
                                                    const float* __restrict__ cw,
                                                    int* __restrict__ cnt,
                                                    int* __restrict__ tok,
                                                    float* __restrict__ wl){
  int e = blockIdx.x;
  int tid = threadIdx.x, lane = tid & 63, wave = tid >> 6;
  __shared__ int wsum[4];
  int running = 0;
  for (int base = 0; base < T_TOK * TOPK; base += 256){
    int i = base + tid;
    bool m = (ce[i] == e);
    unsigned long long bal = __ballot(m);
    int woff = __popcll(bal & ((1ull << lane) - 1ull));
    if (lane == 0) wsum[wave] = __popcll(bal);
    __syncthreads();
    int wbase = 0;
#pragma unroll
    for (int wv = 0; wv < 4; wv++) if (wv < wave) wbase += wsum[wv];
    int btot = wsum[0] + wsum[1] + wsum[2] + wsum[3];
    if (m){
      int t = i / TOPK, k = i - t * TOPK;
      int pos = running + wbase + woff;
      tok[e * T_TOK + pos] = (t << 3) | k;
      wl[e * T_TOK + pos] = cw[i];
    }
    running += btot;
    __syncthreads();
  }
  if (tid == 0) cnt[e] = running;
}

// dense tile plan: plan[1+i] = (tile_base<<8)|expert
__global__ __launch_bounds__(256) void plan_kernel(const int* __restrict__ cnt,
                                                   int* __restrict__ plan){
  int tid = threadIdx.x;
  if (tid < PLAN_MAX) plan[1 + tid] = -1;
  __syncthreads();
  if (tid == 0){
    int n = 0;
    for (int e = 0; e < NEXP; e++){
      int c = cnt[e];
      for (int tb = 0; tb < c; tb += 128) plan[1 + n++] = (tb << 8) | e;
    }
    plan[0] = n;
  }
}

// ---- m97-style core: 128x128 block tile, BK=32, 4 waves in 2x2, 4x4 MFMA acc/wave ----
__device__ __forceinline__ void gemm_core(
    const char* gA0, const char* gA1, const char* gB0, const char* gB1,
    u16* lA, u16* lB, int iters, int tid, int wrow, int wcol, int quad, int l16,
    f32x4 acc[4][4])
{
  char* dA0 = (char*)lA + tid*16;
  char* dA1 = (char*)lA + 4096 + tid*16;
  char* dB0 = (char*)lB + tid*16;
  char* dB1 = (char*)lB + 4096 + tid*16;
  for (int it = 0; it < iters; ++it){
    gll16(gA0, dA0); gll16(gA1, dA1);
    gll16(gB0, dB0); gll16(gB1, dB1);
    gA0 += 64; gA1 += 64; gB0 += 64; gB1 += 64;
    __syncthreads();
    bf16x8 af[4], bfr[4];
#pragma unroll
    for (int mt = 0; mt < 4; mt++) af[mt] = *(const bf16x8*)&lA[(wrow + mt*16 + l16)*32 + quad*8];
#pragma unroll
    for (int nt = 0; nt < 4; nt++) bfr[nt] = *(const bf16x8*)&lB[(wcol + nt*16 + l16)*32 + quad*8];
#pragma unroll
    for (int mt = 0; mt < 4; mt++)
#pragma unroll
      for (int nt = 0; nt < 4; nt++)
        acc[mt][nt] = __builtin_amdgcn_mfma_f32_16x16x32_bf16(af[mt], bfr[nt], acc[mt][nt], 0, 0, 0);
    __syncthreads();
  }
}

#define ACC_INIT f32x4 acc[4][4]; \
  _Pragma("unroll") for (int i_ = 0; i_ < 4; i_++) \
  _Pragma("unroll") for (int j_ = 0; j_ < 4; j_++) acc[i_][j_] = (f32x4){0.f,0.f,0.f,0.f};

// unified up: blocks [0,256) = shared up (16x16 tiles); [256, 256+PLAN_MAX*4) = expert up.
__global__ __launch_bounds__(256) void up_kernel(const u16* __restrict__ xb,
                                                 const u16* __restrict__ supb,
                                                 const u16* __restrict__ upb,
                                                 const int* __restrict__ cnt,
                                                 const int* __restrict__ tok,
                                                 const float* __restrict__ wl,
                                                 const int* __restrict__ plan,
                                                 u16* __restrict__ shh,
                                                 u16* __restrict__ hws){
  __shared__ u16 lA[128*32], lB[128*32];
  int tid = threadIdx.x;
  int lane = tid & 63, wave = tid >> 6, quad = lane >> 4, l16 = lane & 15;
  int wrow = (wave >> 1)*64, wcol = (wave & 1)*64;
  int srow = tid >> 2, sseg = (tid & 3)*16;

  if (blockIdx.x < 256){
    // ---- shared up ----
    int bm = (blockIdx.x >> 4)*128, bn = (blockIdx.x & 15)*128;
    const char* gA0 = (const char*)(xb + (size_t)(bm + srow)*HID) + sseg;
    const char* gA1 = (const char*)(xb + (size_t)(bm + 64 + srow)*HID) + sseg;
    const char* gB0 = (const char*)(supb + (size_t)(bn + srow)*HID) + sseg;
    const char* gB1 = (const char*)(supb + (size_t)(bn + 64 + srow)*HID) + sseg;
    ACC_INIT;
    gemm_core(gA0, gA1, gB0, gB1, lA, lB, HID/32, tid, wrow, wcol, quad, l16, acc);
#pragma unroll
    for (int mt = 0; mt < 4; mt++)
#pragma unroll
      for (int nt = 0; nt < 4; nt++)
#pragma unroll
        for (int r = 0; r < 4; r++){
          int m = bm + wrow + mt*16 + quad*4 + r;
          int n = bn + wcol + nt*16 + l16;
          float v = acc[mt][nt][r]; v = fmaxf(v, 0.f); v *= v;
          shh[(size_t)m*SI + n] = f2bf(v);
        }
    return;
  }
  // ---- expert up ----
  int idx = blockIdx.x - 256;
  int pv = plan[1 + (idx >> 2)];
  if (pv < 0) return;
  int e = pv & 255;
  int tb = pv >> 8;
  int c = cnt[e];
  int bn = (idx & 3) * 128;
  const int* tl = tok + e * T_TOK;
  const float* wle = wl + e * T_TOK;
  int s0 = tb + srow;      if (s0 > c-1) s0 = c-1;
  int s1 = tb + 64 + srow; if (s1 > c-1) s1 = c-1;
  int t0 = tl[s0] >> 3, t1 = tl[s1] >> 3;
  const char* gA0 = (const char*)(xb + (size_t)t0*HID) + sseg;
  const char* gA1 = (const char*)(xb + (size_t)t1*HID) + sseg;
  const u16* Bb = upb + (size_t)e * IM * HID;
  const char* gB0 = (const char*)(Bb + (size_t)(bn + srow)*HID) + sseg;
  const char* gB1 = (const char*)(Bb + (size_t)(bn + 64 + srow)*HID) + sseg;
  ACC_INIT;
  gemm_core(gA0, gA1, gB0, gB1, lA, lB, HID/32, tid, wrow, wcol, quad, l16, acc);
#pragma unroll
  for (int mt = 0; mt < 4; mt++)
#pragma unroll
    for (int r = 0; r < 4; r++){
      int s = tb + wrow + mt*16 + quad*4 + r;
      if (s < c){
        int code = tl[s];
        float w = wle[s];
        size_t hb = ((size_t)(code >> 3) * TOPK + (code & 7)) * IM;
#pragma unroll
        for (int nt = 0; nt < 4; nt++){
          float v = acc[mt][nt][r]; v = fmaxf(v, 0.f); v = v * v * w;
          hws[hb + bn + (wcol + nt*16 + l16)] = f2bf(v);
        }
      }
    }
}

// shared down: out[2048][1024] = H[2048][2048] . W[1024][2048]^T (fp32)
// MUST run before expert_down_kernel (dws aliases sdnb+shh tail).
__global__ __launch_bounds__(256) void sh_down_kernel(const u16* __restrict__ A,
                                                      const u16* __restrict__ B,
                                                      float* __restrict__ C){
  __shared__ u16 lA[128*32], lB[128*32];
  int tid = threadIdx.x;
  int bm = blockIdx.x*128, bn = blockIdx.y*128;
  int lane = tid & 63, wave = tid >> 6, quad = lane >> 4, l16 = lane & 15;
  int wrow = (wave >> 1)*64, wcol = (wave & 1)*64;
  int srow = tid >> 2, sseg = (tid & 3)*16;
  const char* gA0 = (const char*)(A + (size_t)(bm + srow)*SI) + sseg;
  const char* gA1 = (const char*)(A + (size_t)(bm + 64 + srow)*SI) + sseg;
  const char* gB0 = (const char*)(B + (size_t)(bn + srow)*SI) + sseg;
  const char* gB1 = (const char*)(B + (size_t)(bn + 64 + srow)*SI) + sseg;
  ACC_INIT;
  gemm_core(gA0, gA1, gB0, gB1, lA, lB, SI/32, tid, wrow, wcol, quad, l16, acc);
#pragma unroll
  for (int mt = 0; mt < 4; mt++)
#pragma unroll
    for (int nt = 0; nt < 4; nt++)
#pragma unroll
      for (int r = 0; r < 4; r++){
        int m = bm + wrow + mt*16 + quad*4 + r;
        int n = bn + wcol + nt*16 + l16;
        C[(size_t)m*HID + n] = acc[mt][nt][r];
      }
}

// expert down: dws[t*6+k][1024] = h_slot . down_e^T (fp32, no atomics)
__global__ __launch_bounds__(256) void expert_down_kernel(const u16* __restrict__ hws,
                                                          const u16* __restrict__ dnb,
                                                          const int* __restrict__ cnt,
                                                          const int* __restrict__ tok,
                                                          const int* __restrict__ plan,
                                                          float* __restrict__ dws){
  int pv = plan[1 + blockIdx.x];
  if (pv < 0) return;
  int e = pv & 255;
  int tb = pv >> 8;
  int c = cnt[e];
  int bn = blockIdx.y * 128;
  const int* tl = tok + e * T_TOK;
  __shared__ u16 lA[128*32], lB[128*32];
  int tid = threadIdx.x;
  int lane = tid & 63, wave = tid >> 6, quad = lane >> 4, l16 = lane & 15;
  int wrow = (wave >> 1)*64, wcol = (wave & 1)*64;
  int srow = tid >> 2, sseg = (tid & 3)*16;
  int s0 = tb + srow;      if (s0 > c-1) s0 = c-1;
  int s1 = tb + 64 + srow; if (s1 > c-1) s1 = c-1;
  int c0 = tl[s0], c1 = tl[s1];
  const char* gA0 = (const char*)(hws + ((size_t)(c0 >> 3)*TOPK + (c0 & 7))*IM) + sseg;
  const char* gA1 = (const char*)(hws + ((size_t)(c1 >> 3)*TOPK + (c1 & 7))*IM) + sseg;
  const u16* Bb = dnb + (size_t)e * HID * IM;
  const char* gB0 = (const char*)(Bb + (size_t)(bn + srow)*IM) + sseg;
  const char* gB1 = (const char*)(Bb + (size_t)(bn + 64 + srow)*IM) + sseg;
  ACC_INIT;
  gemm_core(gA0, gA1, gB0, gB1, lA, lB, IM/32, tid, wrow, wcol, quad, l16, acc);
#pragma unroll
  for (int mt = 0; mt < 4; mt++)
#pragma unroll
    for (int r = 0; r < 4; r++){
      int s = tb + wrow + mt*16 + quad*4 + r;
      if (s < c){
        int code = tl[s];
        size_t db = ((size_t)(code >> 3) * TOPK + (code & 7)) * HID;
#pragma unroll
        for (int nt = 0; nt < 4; nt++)
          dws[db + bn + (wcol + nt*16 + l16)] = acc[mt][nt][r];
      }
    }
}

// out[t][h] += sum_k dws[t*6+k][h]
__global__ __launch_bounds__(256) void reduce_kernel(const float4* __restrict__ dws,
                                                     float4* __restrict__ out){
  int i = blockIdx.x * 256 + threadIdx.x;
  int t = i >> 8;
  int col = i & 255;
  const float4* p = dws + (size_t)t * TOPK * 256 + col;
  float4 s = out[i];
#pragma unroll
  for (int k = 0; k < TOPK; k++){
    float4 v = p[(size_t)k * 256];
    s.x += v.x; s.y += v.y; s.z += v.z; s.w += v.w;
  }
  out[i] = s;
}

extern "C" void kernel_launch(void* const* d_in, const int* in_sizes, int n_in,
                              void* d_out, int out_size, void* d_ws, size_t ws_size,
                              hipStream_t stream) {
  const float* x    = (const float*)d_in[0];
  const float* gate = (const float*)d_in[1];
  const float* eb   = (const float*)d_in[2];
  const float* upw  = (const float*)d_in[3];
  const float* dnw  = (const float*)d_in[4];
  const float* supw = (const float*)d_in[5];
  const float* sdnw = (const float*)d_in[6];
  float* out = (float*)d_out;

  // ---- workspace layout (explicit bytes; R5-proven 96.6 MiB total) ----
  char* w = (char*)d_ws;
  size_t o = 0;
  int*   cnt  = (int*)(w + o);   o += 1024;
  int*   plan = (int*)(w + o);   o += 1024;
  int*   ce   = (int*)(w + o);   o += 49152;     // 12288 * 4
  float* cw   = (float*)(w + o); o += 49152;
  int*   tok  = (int*)(w + o);   o += 262144;    // 32*2048*4
  float* wl   = (float*)(w + o); o += 262144;
  u16*   xb   = (u16*)(w + o);   o += 4194304;   // 2048*1024*2   (live through up)
  u16*   dnb  = (u16*)(w + o);   o += 33554432;  // 32*1024*512*2 (live in expert_down)
  u16*   hws  = (u16*)(w + o);   o += 12582912;  // 2048*6*512*2  (live in expert_down)
  // aliased region: dead by the time expert_down writes dws.
  // upb 33,554,432 + supb 4,194,304 + sdnb 4,194,304 + shh 8,388,608 = 50,331,648
  // dws = 2048*6*1024*4 = 50,331,648 bytes. EXACT fit (sh_down must precede expert_down).
  size_t region = o;
  u16*   upb  = (u16*)(w + o);   o += 33554432;
  u16*   supb = (u16*)(w + o);   o += 4194304;
  u16*   sdnb = (u16*)(w + o);   o += 4194304;
  u16*   shh  = (u16*)(w + o);   o += 8388608;
  float* dws  = (float*)(w + region);

  // phase1: fused cvt (x|upw|dnw|supw|sdnw) + router
  phase1_kernel<<<CVT_BLOCKS + T_TOK/4, 256, 0, stream>>>(
      (const float4*)x, (const float4*)upw, (const float4*)dnw,
      (const float4*)supw, (const float4*)sdnw,
      (ushort4*)xb, (ushort4*)upb, (ushort4*)dnb, (ushort4*)supb, (ushort4*)sdnb,
      gate, eb, ce, cw);

  build_kernel<<<NEXP, 256, 0, stream>>>(ce, cw, cnt, tok, wl);
  plan_kernel<<<1, 256, 0, stream>>>(cnt, plan);

  up_kernel<<<256 + PLAN_MAX*4, 256, 0, stream>>>(xb, supb, upb, cnt, tok, wl, plan, shh, hws);

  sh_down_kernel<<<dim3(T_TOK/128, HID/128), 256, 0, stream>>>(shh, sdnb, out);
  expert_down_kernel<<<dim3(PLAN_MAX, HID/128), 256, 0, stream>>>(hws, dnb, cnt, tok, plan, dws);

  reduce_kernel<<<(T_TOK * HID / 4) / 256, 256, 0, stream>>>((const float4*)dws, (float4*)out);
}